// Round 2
// baseline (11622.820 us; speedup 1.0000x reference)
//
#include <hip/hip_runtime.h>
#include <math.h>

#define BS 256
#define NN 2048
#define KK 64
#define KP1 65
#define NTHREADS 512
#define RPT 4              // rows per thread = NN / NTHREADS
#define MAX_ITER 200
#define NSEG 4             // 4 segments of 16 along j (j=0..63); j=64 handled separately

// ---- monotone float<->uint encoding for atomic min/max ----
__device__ __forceinline__ unsigned enc_f32(float f) {
    unsigned b = __float_as_uint(f);
    return b ^ (unsigned)(((int)b >> 31) | (int)0x80000000);
}
__device__ __forceinline__ float dec_f32(unsigned e) {
    unsigned b = (e & 0x80000000u) ? (e & 0x7FFFFFFFu) : ~e;
    return __uint_as_float(b);
}

// ---- kernel 1: global min/max of scores (ignoring -inf for min), count -inf ----
__global__ void minmax_kernel(const float* __restrict__ s,
                              unsigned* __restrict__ maxenc,
                              unsigned* __restrict__ minenc,
                              unsigned* __restrict__ infc) {
    int tid = blockIdx.x * blockDim.x + threadIdx.x;
    int stride = gridDim.x * blockDim.x;
    float mx = -INFINITY, mn = INFINITY;
    unsigned cnt = 0;
    for (int i = tid; i < BS * NN; i += stride) {
        float v = s[i];
        if (isinf(v) && v < 0.0f) cnt++;
        else { mx = fmaxf(mx, v); mn = fminf(mn, v); }
    }
    for (int off = 32; off > 0; off >>= 1) {
        mx = fmaxf(mx, __shfl_down(mx, off));
        mn = fminf(mn, __shfl_down(mn, off));
        cnt += __shfl_down(cnt, off);
    }
    __shared__ float smx[8], smn[8];
    __shared__ unsigned scnt[8];
    int wid = threadIdx.x >> 6, lane = threadIdx.x & 63;
    if (lane == 0) { smx[wid] = mx; smn[wid] = mn; scnt[wid] = cnt; }
    __syncthreads();
    if (threadIdx.x == 0) {
        int nw = blockDim.x >> 6;
        for (int w = 1; w < nw; w++) { mx = fmaxf(mx, smx[w]); mn = fminf(mn, smn[w]); cnt += scnt[w]; }
        atomicMax(maxenc, enc_f32(mx));
        atomicMin(minenc, enc_f32(mn));
        if (cnt) atomicAdd(infc, cnt);
    }
}

// ---- kernel 2: per-batch sort + tau + Gamma0 sums + 200-iter Sinkhorn + outputs ----
// G regenerated per-iteration via anchored multiplicative recurrence (no exp in loop,
// no G[65] array). Registers: vloc[65]+cp[65]+anchors[36] ~ 200 VGPR -> force 2 waves/EU
// (256 VGPR cap) so nothing spills.
__attribute__((amdgpu_waves_per_eu(2)))
__global__ void __launch_bounds__(NTHREADS)
sink_main(const float* __restrict__ scores, const float* __restrict__ W,
          float* __restrict__ out,
          const unsigned* __restrict__ maxenc, const unsigned* __restrict__ minenc,
          const unsigned* __restrict__ infc, double* __restrict__ norm_acc)
{
    const int tid = threadIdx.x;
    const int b = blockIdx.x;

    __shared__ float ss[NN];                                    // filled scores
    __shared__ float srt[NN];                                   // sort buffer
    __shared__ float v_sh[68] __attribute__((aligned(16)));     // v (65 used)
    __shared__ float vprev_sh[68];                              // v_{t-1} (for final u)
    __shared__ float slab[2][32 * KP1] __attribute__((aligned(16))); // colsum partials
    __shared__ double red_sh[NTHREADS];
    __shared__ float recS_sh[KK];
    __shared__ float topk_sh[KK];

    const float LOG2E  = 1.4426950408889634f;
    const float inv_n  = 1.0f / 2048.0f;         // exact
    const float nu_last = 1984.0f / 2048.0f;     // exact

    // global scalars
    float smax = dec_f32(*maxenc);
    float smin = dec_f32(*minenc);
    unsigned icnt = *infc;
    float filled = smin - (smax - smin);
    float slo = (icnt > 0) ? filled : smin;
    // C.max() is attained at an extreme s with anchor 0 or 64 (convexity)
    float cA = slo * slo, cB = (slo - 64.0f) * (slo - 64.0f);
    float cC = smax * smax, cD = (smax - 64.0f) * (smax - 64.0f);
    float Cmax = fmaxf(fmaxf(cA, cB), fmaxf(cC, cD));
    float negc2 = -(10.0f * LOG2E) / Cmax;       // exp(-C/Cmax/0.1) == exp2(d*d*negc2)
    float step = __builtin_amdgcn_exp2f(2.0f * negc2);  // t_{j+1}/t_j, wave-uniform

    // load + -inf fill
    for (int i = tid; i < NN; i += NTHREADS) {
        float v = scores[(size_t)b * NN + i];
        if (isinf(v) && v < 0.0f) v = filled;
        ss[i] = v; srt[i] = v;
    }
    __syncthreads();

    // bitonic sort (ascending), 1024 pairs/stage over 512 threads
    for (int size = 2; size <= NN; size <<= 1) {
        for (int stride = size >> 1; stride > 0; stride >>= 1) {
            #pragma unroll
            for (int pp = 0; pp < (NN / 2) / NTHREADS; pp++) {
                int p = tid + pp * NTHREADS;
                int lo = ((p & ~(stride - 1)) << 1) | (p & (stride - 1));
                int hi = lo + stride;
                bool up = ((lo & size) == 0);
                float x = srt[lo], y = srt[hi];
                if ((x > y) == up) { srt[lo] = y; srt[hi] = x; }
            }
            __syncthreads();
        }
    }

    // topk (descending) from sorted
    for (int k = tid; k < KK; k += NTHREADS) topk_sh[k] = srt[NN - 1 - k];

    // tau = sum(sorted * W), fp64 accumulate
    double tp = 0.0;
    for (int i = tid; i < NN; i += NTHREADS) tp += (double)srt[i] * (double)W[i];
    red_sh[tid] = tp;
    __syncthreads();
    for (int s2 = NTHREADS / 2; s2 > 0; s2 >>= 1) {
        if (tid < s2) red_sh[tid] += red_sh[tid + s2];
        __syncthreads();
    }
    float tau = (float)red_sh[0];
    float lt = LOG2E / tau;                      // sigma = 1/(1+exp2(|d|*lt))

    // ---- per-row recurrence anchors (iteration-invariant) ----
    // d_j = si - (64 - j) = d0 + j;  g_j = exp2(negc2*d_j^2)
    // t_j = g_{j+1}/g_j = exp2(negc2*(2*d_j+1));  t_{j+1} = t_j*step
    // anchors at j = 0,16,32,48 (g,t) and j = 64 (g only)
    float ganc[RPT][5], tanc[RPT][4];
    #pragma unroll
    for (int r = 0; r < RPT; r++) {
        float si = ss[tid + r * NTHREADS];
        #pragma unroll
        for (int a = 0; a < 5; a++) {
            float d = si - 64.0f + 16.0f * (float)a;
            ganc[r][a] = __builtin_amdgcn_exp2f(negc2 * d * d);
            if (a < 4) tanc[r][a] = __builtin_amdgcn_exp2f(negc2 * (2.0f * d + 1.0f));
        }
    }

    // init v, zero both slabs
    for (int j = tid; j < KP1; j += NTHREADS) v_sh[j] = 1.0f / 65.0f;
    for (int q = tid; q < 2 * 32 * KP1; q += NTHREADS) ((float*)slab)[q] = 0.0f;
    __syncthreads();

    const int g32 = tid & 31;

    // Gamma0 column sums S_k (into slab[1]; slab[1] gets re-zeroed by iter t=0)
    {
        float part[KK];
        #pragma unroll
        for (int k = 0; k < KK; k++) part[k] = 0.0f;
        for (int r = 0; r < RPT; r++) {
            float si = ss[tid + r * NTHREADS];
            #pragma unroll
            for (int k = 0; k < KK; k++) {
                float d = fabsf(topk_sh[k] - si);
                float e = __builtin_amdgcn_exp2f(d * lt);
                float sg = 1.0f / (1.0f + e) + 1e-20f;
                part[k] += sg;
            }
        }
        #pragma unroll
        for (int k = 0; k < KK; k++) atomicAdd(&slab[1][g32 * KP1 + k], part[k]);
    }
    __syncthreads();
    if (tid < KK) {
        float sum = 0.0f;
        #pragma unroll
        for (int g = 0; g < 32; g++) sum += slab[1][g * KP1 + tid];
        recS_sh[tid] = 1.0f / sum;
    }
    __syncthreads();

    // ---- Sinkhorn: 200 iterations, zero transcendentals in the loop ----
    float vloc[KP1], cp[KP1];

    for (int t = 0; t < MAX_ITER; t++) {
        float* sl  = &slab[t & 1][0];
        float* slz = &slab[(t + 1) & 1][0];
        #pragma unroll
        for (int q = 0; q < 16; q++) {
            float4 vv = ((const float4*)v_sh)[q];
            vloc[4 * q + 0] = vv.x; vloc[4 * q + 1] = vv.y;
            vloc[4 * q + 2] = vv.z; vloc[4 * q + 3] = vv.w;
        }
        vloc[64] = v_sh[64];
        #pragma unroll
        for (int j = 0; j < KP1; j++) cp[j] = 0.0f;
        // zero next-iteration slab (its readers finished before the entry barrier)
        for (int q = tid; q < 32 * KP1; q += NTHREADS) slz[q] = 0.0f;

        #pragma unroll
        for (int r = 0; r < RPT; r++) {
            // pass 1: rowsum = sum_j g_j * v_j   (recurrence, 4 indep segment chains)
            float acc[NSEG] = {0.0f, 0.0f, 0.0f, 0.0f};
            #pragma unroll
            for (int a = 0; a < NSEG; a++) {
                float g = ganc[r][a], tt = tanc[r][a];
                #pragma unroll
                for (int jj = 0; jj < 16; jj++) {
                    acc[a] = fmaf(g, vloc[a * 16 + jj], acc[a]);
                    g *= tt; tt *= step;
                }
            }
            float rowsum = ((acc[0] + acc[1]) + (acc[2] + acc[3]))
                         + ganc[r][4] * vloc[64];
            float u = inv_n / rowsum;                    // IEEE div, matches ref
            // pass 2: cp_j += g_j * u   (re-run recurrence)
            #pragma unroll
            for (int a = 0; a < NSEG; a++) {
                float g = ganc[r][a], tt = tanc[r][a];
                #pragma unroll
                for (int jj = 0; jj < 16; jj++) {
                    int j = a * 16 + jj;
                    cp[j] = fmaf(g, u, cp[j]);
                    g *= tt; tt *= step;
                }
            }
            cp[64] = fmaf(ganc[r][4], u, cp[64]);
        }
        #pragma unroll
        for (int j = 0; j < KP1; j++) atomicAdd(&sl[g32 * KP1 + j], cp[j]);
        __syncthreads();
        if (tid < KP1) {
            float cs = 0.0f;
            #pragma unroll
            for (int g = 0; g < 32; g++) cs += sl[g * KP1 + tid];  // (g+tid)%32: conflict-free
            float nuj = (tid == KK) ? nu_last : inv_n;
            vprev_sh[tid] = v_sh[tid];                   // keep v_{199} for final u
            v_sh[tid] = nuj / cs;
        }
        __syncthreads();
    }

    // ---- final: Gamma = u*G*v, A = Gamma[:, :, :K]*n, norm vs Gamma0 ----
    // pass A: all four u's via recurrence against v_prev (vp); then vp is dead.
    {
        float vp[KP1];
        #pragma unroll
        for (int j = 0; j < KP1; j++) vp[j] = vprev_sh[j];

        float uf[RPT];
        #pragma unroll
        for (int r = 0; r < RPT; r++) {
            float acc[NSEG] = {0.0f, 0.0f, 0.0f, 0.0f};
            #pragma unroll
            for (int a = 0; a < NSEG; a++) {
                float g = ganc[r][a], tt = tanc[r][a];
                #pragma unroll
                for (int jj = 0; jj < 16; jj++) {
                    acc[a] = fmaf(g, vp[a * 16 + jj], acc[a]);
                    g *= tt; tt *= step;
                }
            }
            float rowsum = ((acc[0] + acc[1]) + (acc[2] + acc[3]))
                         + ganc[r][4] * vp[64];
            uf[r] = inv_n / rowsum;                      // identical to iter-200 u
        }

        // pass B: outputs + norm, exact exp per element (runs once)
        #pragma unroll
        for (int j = 0; j < KP1; j++) vloc[j] = v_sh[j];

        double npart = 0.0;
        for (int r = 0; r < RPT; r++) {
            int i = tid + r * NTHREADS;
            float si = ss[i];
            float u = uf[r];

            float g0sum = 0.0f;
            float* orow = out + ((size_t)b * NN + i) * KK;
            #pragma unroll
            for (int q = 0; q < 16; q++) {
                float4 o;
                float d_, g_, gm, dd, e, sg, g0, df;
                #define DO_K(kk_, fld) { const int k = 4 * q + kk_;            \
                    d_ = si - (float)(KK - k);                                 \
                    g_ = __builtin_amdgcn_exp2f(negc2 * d_ * d_);              \
                    gm = (u * g_) * vloc[k];                                   \
                    dd = fabsf(topk_sh[k] - si);                               \
                    e  = __builtin_amdgcn_exp2f(dd * lt);                      \
                    sg = 1.0f / (1.0f + e) + 1e-20f;                           \
                    g0 = (sg * recS_sh[k]) * inv_n;                            \
                    g0sum += g0;                                               \
                    df = gm - g0; npart += (double)df * (double)df;            \
                    o.fld = gm * 2048.0f; }
                DO_K(0, x) DO_K(1, y) DO_K(2, z) DO_K(3, w)
                #undef DO_K
                ((float4*)orow)[q] = o;
            }
            float last = inv_n - g0sum;
            last = fminf(fmaxf(last, 1e-20f), 1.0f);     // clip(.,1e-20,1-1e-20)
            float g64 = __builtin_amdgcn_exp2f(negc2 * si * si);   // j=64: anchor 0
            float gm64 = (u * g64) * vloc[64];
            float df = gm64 - last;
            npart += (double)df * (double)df;
        }

        __syncthreads();
        red_sh[tid] = npart;
        __syncthreads();
        for (int s2 = NTHREADS / 2; s2 > 0; s2 >>= 1) {
            if (tid < s2) red_sh[tid] += red_sh[tid + s2];
            __syncthreads();
        }
        if (tid == 0) atomicAdd(norm_acc, red_sh[0]);
    }
}

// ---- kernel 3: finalize norm ----
__global__ void finalize_kernel(const double* __restrict__ norm_acc, float* __restrict__ out) {
    if (threadIdx.x == 0 && blockIdx.x == 0)
        out[(size_t)BS * NN * KK] = (float)sqrt(*norm_acc);
}

extern "C" void kernel_launch(void* const* d_in, const int* in_sizes, int n_in,
                              void* d_out, int out_size, void* d_ws, size_t ws_size,
                              hipStream_t stream) {
    const float* scores = (const float*)d_in[0];
    const float* W = (const float*)d_in[1];
    float* out = (float*)d_out;

    // ws layout: [0..3] max_enc(init 0), [4..7] inf_count(init 0),
    //            [8..15] norm_acc double(init 0), [16..19] min_enc(init 0xFFFFFFFF)
    unsigned* maxenc = (unsigned*)d_ws;
    unsigned* infc   = maxenc + 1;
    double*  nacc    = (double*)((char*)d_ws + 8);
    unsigned* minenc = (unsigned*)((char*)d_ws + 16);

    hipMemsetAsync(d_ws, 0, 16, stream);
    hipMemsetAsync((char*)d_ws + 16, 0xFF, 4, stream);

    hipLaunchKernelGGL(minmax_kernel, dim3(256), dim3(256), 0, stream,
                       scores, maxenc, minenc, infc);
    hipLaunchKernelGGL(sink_main, dim3(BS), dim3(NTHREADS), 0, stream,
                       scores, W, out, maxenc, minenc, infc, nacc);
    hipLaunchKernelGGL(finalize_kernel, dim3(1), dim3(64), 0, stream, nacc, out);
}

// Round 3
// 10073.970 us; speedup vs baseline: 1.1537x; 1.1537x over previous
//
#include <hip/hip_runtime.h>
#include <math.h>

#define BS 256
#define NN 2048
#define KK 64
#define KP1 65
#define NTHREADS 512
#define NTEAMS 128           // NTHREADS / 4 teams; each team of 4 lanes owns rows
#define ROWS_PT 16           // NN / NTEAMS rows per team
#define MAX_ITER 200
#define SLABR 8              // LDS reduction slab rows

// ---- monotone float<->uint encoding for atomic min/max ----
__device__ __forceinline__ unsigned enc_f32(float f) {
    unsigned b = __float_as_uint(f);
    return b ^ (unsigned)(((int)b >> 31) | (int)0x80000000);
}
__device__ __forceinline__ float dec_f32(unsigned e) {
    unsigned b = (e & 0x80000000u) ? (e & 0x7FFFFFFFu) : ~e;
    return __uint_as_float(b);
}

// ---- kernel 1: global min/max of scores (ignoring -inf for min), count -inf ----
__global__ void minmax_kernel(const float* __restrict__ s,
                              unsigned* __restrict__ maxenc,
                              unsigned* __restrict__ minenc,
                              unsigned* __restrict__ infc) {
    int tid = blockIdx.x * blockDim.x + threadIdx.x;
    int stride = gridDim.x * blockDim.x;
    float mx = -INFINITY, mn = INFINITY;
    unsigned cnt = 0;
    for (int i = tid; i < BS * NN; i += stride) {
        float v = s[i];
        if (isinf(v) && v < 0.0f) cnt++;
        else { mx = fmaxf(mx, v); mn = fminf(mn, v); }
    }
    for (int off = 32; off > 0; off >>= 1) {
        mx = fmaxf(mx, __shfl_down(mx, off));
        mn = fminf(mn, __shfl_down(mn, off));
        cnt += __shfl_down(cnt, off);
    }
    __shared__ float smx[8], smn[8];
    __shared__ unsigned scnt[8];
    int wid = threadIdx.x >> 6, lane = threadIdx.x & 63;
    if (lane == 0) { smx[wid] = mx; smn[wid] = mn; scnt[wid] = cnt; }
    __syncthreads();
    if (threadIdx.x == 0) {
        int nw = blockDim.x >> 6;
        for (int w = 1; w < nw; w++) { mx = fmaxf(mx, smx[w]); mn = fminf(mn, smn[w]); cnt += scnt[w]; }
        atomicMax(maxenc, enc_f32(mx));
        atomicMin(minenc, enc_f32(mn));
        if (cnt) atomicAdd(infc, cnt);
    }
}

// ---- kernel 2: per-batch sort + tau + Gamma0 + 200-iter Sinkhorn + outputs ----
// Team layout: 4 lanes per row-team; lane seg owns columns [seg*16, seg*16+16)
// (seg==3 additionally owns j=64, whose G value is the natural endpoint of its
// recurrence). Per-thread live state ~90 VGPRs -> no spills at default cap.
__global__ void __launch_bounds__(NTHREADS, 1)
sink_main(const float* __restrict__ scores, const float* __restrict__ W,
          float* __restrict__ out,
          const unsigned* __restrict__ maxenc, const unsigned* __restrict__ minenc,
          const unsigned* __restrict__ infc, double* __restrict__ norm_acc)
{
    const int tid  = threadIdx.x;
    const int b    = blockIdx.x;
    const int team = tid >> 2;     // 0..127
    const int seg  = tid & 3;      // 0..3
    const int h8   = team & 7;     // slab row

    __shared__ float ss[NN];                                     // filled scores
    __shared__ float srt[NN];                                    // sort buffer
    __shared__ float v_sh[68] __attribute__((aligned(16)));      // v (65 used)
    __shared__ float vprev_sh[68];                               // v_{t-1}
    __shared__ float slab[2][SLABR * KP1] __attribute__((aligned(16)));
    __shared__ double red_sh[NTHREADS];
    __shared__ float recS_sh[KK];
    __shared__ float topk_sh[KK];

    const float LOG2E   = 1.4426950408889634f;
    const float inv_n   = 1.0f / 2048.0f;        // exact
    const float nu_last = 1984.0f / 2048.0f;     // exact

    // global scalars
    float smax = dec_f32(*maxenc);
    float smin = dec_f32(*minenc);
    unsigned icnt = *infc;
    float filled = smin - (smax - smin);
    float slo = (icnt > 0) ? filled : smin;
    // C.max() attained at an extreme s with anchor 0 or 64 (convexity)
    float cA = slo * slo, cB = (slo - 64.0f) * (slo - 64.0f);
    float cC = smax * smax, cD = (smax - 64.0f) * (smax - 64.0f);
    float Cmax = fmaxf(fmaxf(cA, cB), fmaxf(cC, cD));
    float negc2 = -(10.0f * LOG2E) / Cmax;       // exp(-C/Cmax/0.1) == exp2(d*d*negc2)
    float step = __builtin_amdgcn_exp2f(2.0f * negc2);  // t_{j+1}/t_j, uniform

    // load + -inf fill
    for (int i = tid; i < NN; i += NTHREADS) {
        float v = scores[(size_t)b * NN + i];
        if (isinf(v) && v < 0.0f) v = filled;
        ss[i] = v; srt[i] = v;
    }
    __syncthreads();

    // bitonic sort (ascending)
    for (int size = 2; size <= NN; size <<= 1) {
        for (int stride = size >> 1; stride > 0; stride >>= 1) {
            #pragma unroll
            for (int pp = 0; pp < (NN / 2) / NTHREADS; pp++) {
                int p = tid + pp * NTHREADS;
                int lo = ((p & ~(stride - 1)) << 1) | (p & (stride - 1));
                int hi = lo + stride;
                bool up = ((lo & size) == 0);
                float x = srt[lo], y = srt[hi];
                if ((x > y) == up) { srt[lo] = y; srt[hi] = x; }
            }
            __syncthreads();
        }
    }

    // topk (descending) from sorted
    for (int k = tid; k < KK; k += NTHREADS) topk_sh[k] = srt[NN - 1 - k];

    // tau = sum(sorted * W), fp64 accumulate
    double tp = 0.0;
    for (int i = tid; i < NN; i += NTHREADS) tp += (double)srt[i] * (double)W[i];
    red_sh[tid] = tp;
    __syncthreads();
    for (int s2 = NTHREADS / 2; s2 > 0; s2 >>= 1) {
        if (tid < s2) red_sh[tid] += red_sh[tid + s2];
        __syncthreads();
    }
    float tau = (float)red_sh[0];
    float lt = LOG2E / tau;                      // sigma = 1/(1+exp2(|d|*lt))

    // init v, zero both slabs
    for (int j = tid; j < KP1; j += NTHREADS) v_sh[j] = 1.0f / 65.0f;
    for (int q = tid; q < 2 * SLABR * KP1; q += NTHREADS) ((float*)slab)[q] = 0.0f;
    __syncthreads();

    // ---- Gamma0 column sums S_k into slab[1] (re-zeroed by iter t=0) ----
    {
        float part[16];
        #pragma unroll
        for (int kk = 0; kk < 16; kk++) part[kk] = 0.0f;
        for (int r = 0; r < ROWS_PT; r++) {
            float si = ss[team + NTEAMS * r];
            #pragma unroll
            for (int kk = 0; kk < 16; kk++) {
                int k = seg * 16 + kk;
                float d = fabsf(topk_sh[k] - si);
                float e = __builtin_amdgcn_exp2f(d * lt);
                float sg = 1.0f / (1.0f + e) + 1e-20f;
                part[kk] += sg;
            }
        }
        #pragma unroll
        for (int kk = 0; kk < 16; kk++)
            atomicAdd(&slab[1][h8 * KP1 + seg * 16 + kk], part[kk]);
    }
    __syncthreads();
    if (tid < KK) {
        float sum = 0.0f;
        #pragma unroll
        for (int g = 0; g < SLABR; g++) sum += slab[1][g * KP1 + tid];
        recS_sh[tid] = 1.0f / sum;
    }
    __syncthreads();

    // ---- per-row recurrence anchors (iteration-invariant) ----
    // d_j = si - (64 - j);  g_j = exp2(negc2*d_j^2)
    // t_j = g_{j+1}/g_j = exp2(negc2*(2*d_j+1));  t_{j+1} = t_j*step
    // anchor at this lane's segment start j0 = seg*16
    float ganc[ROWS_PT], tanc[ROWS_PT];
    #pragma unroll
    for (int r = 0; r < ROWS_PT; r++) {
        float si = ss[team + NTEAMS * r];
        float d0 = si - 64.0f + 16.0f * (float)seg;
        ganc[r] = __builtin_amdgcn_exp2f(negc2 * d0 * d0);
        tanc[r] = __builtin_amdgcn_exp2f(negc2 * (2.0f * d0 + 1.0f));
    }

    // ---- Sinkhorn: 200 iterations ----
    for (int t = 0; t < MAX_ITER; t++) {
        float* sl  = &slab[t & 1][0];
        float* slz = &slab[(t + 1) & 1][0];

        float vloc[16], v64, cp[16], cp64;
        #pragma unroll
        for (int q = 0; q < 4; q++) {
            float4 vv = ((const float4*)(v_sh + seg * 16))[q];
            vloc[4 * q + 0] = vv.x; vloc[4 * q + 1] = vv.y;
            vloc[4 * q + 2] = vv.z; vloc[4 * q + 3] = vv.w;
        }
        v64 = v_sh[64];
        #pragma unroll
        for (int j = 0; j < 16; j++) cp[j] = 0.0f;
        cp64 = 0.0f;
        // zero next-iteration slab (readers finished before entry barrier)
        for (int q = tid; q < SLABR * KP1; q += NTHREADS) slz[q] = 0.0f;

        #pragma unroll
        for (int r = 0; r < ROWS_PT; r++) {
            float g = ganc[r], tt = tanc[r];
            float G16[16];
            float p0 = 0.0f, p1 = 0.0f;
            #pragma unroll
            for (int jj = 0; jj < 16; jj += 2) {
                G16[jj] = g;     p0 = fmaf(g, vloc[jj],     p0); g *= tt; tt *= step;
                G16[jj + 1] = g; p1 = fmaf(g, vloc[jj + 1], p1); g *= tt; tt *= step;
            }
            float partial = p0 + p1;
            float g64r = g;                      // == g at j0+16; for seg==3 that's j=64
            if (seg == 3) partial = fmaf(g64r, v64, partial);
            partial += __shfl_xor(partial, 1);
            partial += __shfl_xor(partial, 2);
            float u = inv_n / partial;           // IEEE div, matches ref
            #pragma unroll
            for (int jj = 0; jj < 16; jj++) cp[jj] = fmaf(G16[jj], u, cp[jj]);
            if (seg == 3) cp64 = fmaf(g64r, u, cp64);
        }
        #pragma unroll
        for (int jj = 0; jj < 16; jj++)
            atomicAdd(&sl[h8 * KP1 + seg * 16 + jj], cp[jj]);
        if (seg == 3) atomicAdd(&sl[h8 * KP1 + 64], cp64);
        __syncthreads();
        if (tid < KP1) {
            float cs = 0.0f;
            #pragma unroll
            for (int g = 0; g < SLABR; g++) cs += sl[g * KP1 + tid];
            float nuj = (tid == KK) ? nu_last : inv_n;
            vprev_sh[tid] = v_sh[tid];           // keep v_{199} for final u
            v_sh[tid] = nuj / cs;
        }
        __syncthreads();
    }

    // ---- final: Gamma = u*G*v, A = Gamma[:,:,:K]*n, norm vs Gamma0 ----
    // pass A: final u per row (uses v_prev), recurrence
    float uf[ROWS_PT];
    {
        float vp[16], vp64;
        #pragma unroll
        for (int j = 0; j < 16; j++) vp[j] = vprev_sh[seg * 16 + j];
        vp64 = vprev_sh[64];
        #pragma unroll
        for (int r = 0; r < ROWS_PT; r++) {
            float g = ganc[r], tt = tanc[r];
            float p0 = 0.0f, p1 = 0.0f;
            #pragma unroll
            for (int jj = 0; jj < 16; jj += 2) {
                p0 = fmaf(g, vp[jj],     p0); g *= tt; tt *= step;
                p1 = fmaf(g, vp[jj + 1], p1); g *= tt; tt *= step;
            }
            float partial = p0 + p1;
            if (seg == 3) partial = fmaf(g, vp64, partial);
            partial += __shfl_xor(partial, 1);
            partial += __shfl_xor(partial, 2);
            uf[r] = inv_n / partial;             // identical to iter-200 u
        }
    }
    // pass B: outputs + norm, exact exp per element (runs once)
    {
        float vloc[16], v64;
        #pragma unroll
        for (int j = 0; j < 16; j++) vloc[j] = v_sh[seg * 16 + j];
        v64 = v_sh[64];

        double npart = 0.0;
        #pragma unroll
        for (int r = 0; r < ROWS_PT; r++) {
            int row = team + NTEAMS * r;
            float si = ss[row];
            float u = uf[r];
            float g0sum = 0.0f;
            float* orow = out + ((size_t)b * NN + row) * KK + seg * 16;
            #pragma unroll
            for (int q = 0; q < 4; q++) {
                float4 o;
                #define DO_K(kk_, fld) { const int k = seg * 16 + 4 * q + kk_;  \
                    float d_ = si - (float)(KK - k);                            \
                    float g_ = __builtin_amdgcn_exp2f(negc2 * d_ * d_);         \
                    float gm = (u * g_) * vloc[4 * q + kk_];                    \
                    float dd = fabsf(topk_sh[k] - si);                          \
                    float e  = __builtin_amdgcn_exp2f(dd * lt);                 \
                    float sg = 1.0f / (1.0f + e) + 1e-20f;                      \
                    float g0 = (sg * recS_sh[k]) * inv_n;                       \
                    g0sum += g0;                                                \
                    float df = gm - g0; npart += (double)df * (double)df;       \
                    o.fld = gm * 2048.0f; }
                DO_K(0, x) DO_K(1, y) DO_K(2, z) DO_K(3, w)
                #undef DO_K
                ((float4*)orow)[q] = o;
            }
            float gtot = g0sum;
            gtot += __shfl_xor(gtot, 1);
            gtot += __shfl_xor(gtot, 2);
            if (seg == 3) {
                float last = inv_n - gtot;
                last = fminf(fmaxf(last, 1e-20f), 1.0f);   // clip(.,1e-20,1-1e-20)
                float g64 = __builtin_amdgcn_exp2f(negc2 * si * si);
                float gm64 = (u * g64) * v64;
                float df = gm64 - last;
                npart += (double)df * (double)df;
            }
        }

        __syncthreads();
        red_sh[tid] = npart;
        __syncthreads();
        for (int s2 = NTHREADS / 2; s2 > 0; s2 >>= 1) {
            if (tid < s2) red_sh[tid] += red_sh[tid + s2];
            __syncthreads();
        }
        if (tid == 0) atomicAdd(norm_acc, red_sh[0]);
    }
}

// ---- kernel 3: finalize norm ----
__global__ void finalize_kernel(const double* __restrict__ norm_acc, float* __restrict__ out) {
    if (threadIdx.x == 0 && blockIdx.x == 0)
        out[(size_t)BS * NN * KK] = (float)sqrt(*norm_acc);
}

extern "C" void kernel_launch(void* const* d_in, const int* in_sizes, int n_in,
                              void* d_out, int out_size, void* d_ws, size_t ws_size,
                              hipStream_t stream) {
    const float* scores = (const float*)d_in[0];
    const float* W = (const float*)d_in[1];
    float* out = (float*)d_out;

    // ws layout: [0..3] max_enc(0), [4..7] inf_count(0),
    //            [8..15] norm_acc double(0), [16..19] min_enc(0xFFFFFFFF)
    unsigned* maxenc = (unsigned*)d_ws;
    unsigned* infc   = maxenc + 1;
    double*  nacc    = (double*)((char*)d_ws + 8);
    unsigned* minenc = (unsigned*)((char*)d_ws + 16);

    hipMemsetAsync(d_ws, 0, 16, stream);
    hipMemsetAsync((char*)d_ws + 16, 0xFF, 4, stream);

    hipLaunchKernelGGL(minmax_kernel, dim3(256), dim3(256), 0, stream,
                       scores, maxenc, minenc, infc);
    hipLaunchKernelGGL(sink_main, dim3(BS), dim3(NTHREADS), 0, stream,
                       scores, W, out, maxenc, minenc, infc, nacc);
    hipLaunchKernelGGL(finalize_kernel, dim3(1), dim3(64), 0, stream, nacc, out);
}

// Round 4
// 3437.423 us; speedup vs baseline: 3.3813x; 2.9307x over previous
//
#include <hip/hip_runtime.h>
#include <math.h>

#define BS 256
#define NN 2048
#define KK 64
#define KP1 65
#define NTHREADS 512
#define NTEAMS 128           // NTHREADS/4 teams; 4 lanes per team
#define ROWS_PT 16           // NN / NTEAMS rows per team
#define MAX_ITER 200
#define SLABR 8              // LDS reduction slab rows

// ---- monotone float<->uint encoding for atomic min/max ----
__device__ __forceinline__ unsigned enc_f32(float f) {
    unsigned b = __float_as_uint(f);
    return b ^ (unsigned)(((int)b >> 31) | (int)0x80000000);
}
__device__ __forceinline__ float dec_f32(unsigned e) {
    unsigned b = (e & 0x80000000u) ? (e & 0x7FFFFFFFu) : ~e;
    return __uint_as_float(b);
}

// ---- kernel 1: global min/max of scores (ignoring -inf for min), count -inf ----
__global__ void minmax_kernel(const float* __restrict__ s,
                              unsigned* __restrict__ maxenc,
                              unsigned* __restrict__ minenc,
                              unsigned* __restrict__ infc) {
    int tid = blockIdx.x * blockDim.x + threadIdx.x;
    int stride = gridDim.x * blockDim.x;
    float mx = -INFINITY, mn = INFINITY;
    unsigned cnt = 0;
    for (int i = tid; i < BS * NN; i += stride) {
        float v = s[i];
        if (isinf(v) && v < 0.0f) cnt++;
        else { mx = fmaxf(mx, v); mn = fminf(mn, v); }
    }
    for (int off = 32; off > 0; off >>= 1) {
        mx = fmaxf(mx, __shfl_down(mx, off));
        mn = fminf(mn, __shfl_down(mn, off));
        cnt += __shfl_down(cnt, off);
    }
    __shared__ float smx[8], smn[8];
    __shared__ unsigned scnt[8];
    int wid = threadIdx.x >> 6, lane = threadIdx.x & 63;
    if (lane == 0) { smx[wid] = mx; smn[wid] = mn; scnt[wid] = cnt; }
    __syncthreads();
    if (threadIdx.x == 0) {
        int nw = blockDim.x >> 6;
        for (int w = 1; w < nw; w++) { mx = fmaxf(mx, smx[w]); mn = fminf(mn, smn[w]); cnt += scnt[w]; }
        atomicMax(maxenc, enc_f32(mx));
        atomicMin(minenc, enc_f32(mn));
        if (cnt) atomicAdd(infc, cnt);
    }
}

// ---- kernel 2: per-batch sort + tau + Gamma0 + 200-iter Sinkhorn + outputs ----
// Team layout: 4 lanes per row-team; lane seg owns columns [seg*16, seg*16+16)
// (seg==3 also owns j=64 = endpoint of its recurrence). Anchors live in LDS
// (1 ds_read_b64/row); row loop is rolled so live regs stay ~65 -> no spills.
__global__ void __launch_bounds__(NTHREADS)
sink_main(const float* __restrict__ scores, const float* __restrict__ W,
          float* __restrict__ out,
          const unsigned* __restrict__ maxenc, const unsigned* __restrict__ minenc,
          const unsigned* __restrict__ infc, double* __restrict__ norm_acc)
{
    const int tid  = threadIdx.x;
    const int b    = blockIdx.x;
    const int team = tid >> 2;     // 0..127
    const int seg  = tid & 3;      // 0..3
    const int h8   = team & 7;     // slab row

    __shared__ float ss[NN];                                     // filled scores
    __shared__ float srt[NN];                                    // sort buf; later u per row
    __shared__ float2 anc_sh[NN * 4] __attribute__((aligned(16))); // (g,t) per (row,seg), 64 KB
    __shared__ float v_sh[68] __attribute__((aligned(16)));      // v (65 used)
    __shared__ float vprev_sh[68];                               // v_{t-1}
    __shared__ float slab[2][SLABR * KP1] __attribute__((aligned(16)));
    __shared__ double red_sh[NTHREADS];
    __shared__ float recS_sh[KK];
    __shared__ float topk_sh[KK];

    const float LOG2E   = 1.4426950408889634f;
    const float inv_n   = 1.0f / 2048.0f;        // exact
    const float nu_last = 1984.0f / 2048.0f;     // exact

    // global scalars
    float smax = dec_f32(*maxenc);
    float smin = dec_f32(*minenc);
    unsigned icnt = *infc;
    float filled = smin - (smax - smin);
    float slo = (icnt > 0) ? filled : smin;
    // C.max() attained at an extreme s with anchor 0 or 64 (convexity)
    float cA = slo * slo, cB = (slo - 64.0f) * (slo - 64.0f);
    float cC = smax * smax, cD = (smax - 64.0f) * (smax - 64.0f);
    float Cmax = fmaxf(fmaxf(cA, cB), fmaxf(cC, cD));
    float negc2 = -(10.0f * LOG2E) / Cmax;       // exp(-C/Cmax/0.1) == exp2(d*d*negc2)
    float step = __builtin_amdgcn_exp2f(2.0f * negc2);  // t_{j+1}/t_j, uniform

    // load + -inf fill
    for (int i = tid; i < NN; i += NTHREADS) {
        float v = scores[(size_t)b * NN + i];
        if (isinf(v) && v < 0.0f) v = filled;
        ss[i] = v; srt[i] = v;
    }
    __syncthreads();

    // bitonic sort (ascending)
    for (int size = 2; size <= NN; size <<= 1) {
        for (int stride = size >> 1; stride > 0; stride >>= 1) {
            #pragma unroll
            for (int pp = 0; pp < (NN / 2) / NTHREADS; pp++) {
                int p = tid + pp * NTHREADS;
                int lo = ((p & ~(stride - 1)) << 1) | (p & (stride - 1));
                int hi = lo + stride;
                bool up = ((lo & size) == 0);
                float x = srt[lo], y = srt[hi];
                if ((x > y) == up) { srt[lo] = y; srt[hi] = x; }
            }
            __syncthreads();
        }
    }

    // topk (descending) from sorted
    for (int k = tid; k < KK; k += NTHREADS) topk_sh[k] = srt[NN - 1 - k];

    // tau = sum(sorted * W), fp64 accumulate
    double tp = 0.0;
    for (int i = tid; i < NN; i += NTHREADS) tp += (double)srt[i] * (double)W[i];
    red_sh[tid] = tp;
    __syncthreads();
    for (int s2 = NTHREADS / 2; s2 > 0; s2 >>= 1) {
        if (tid < s2) red_sh[tid] += red_sh[tid + s2];
        __syncthreads();
    }
    float tau = (float)red_sh[0];
    float lt = LOG2E / tau;                      // sigma = 1/(1+exp2(|d|*lt))

    // init v, zero both slabs
    for (int j = tid; j < KP1; j += NTHREADS) v_sh[j] = 1.0f / 65.0f;
    for (int q = tid; q < 2 * SLABR * KP1; q += NTHREADS) ((float*)slab)[q] = 0.0f;

    // ---- anchors into LDS: (g0, t0) at j0 = seg*16 for each of my 16 rows ----
    // d_j = si - (64-j); g_j = exp2(negc2*d_j^2); t_j = exp2(negc2*(2*d_j+1))
    // lane tid, row r -> anc_sh[tid + 512*r]: stride-8B across lanes, conflict-free
    #pragma unroll 1
    for (int r = 0; r < ROWS_PT; r++) {
        float si = ss[team + NTEAMS * r];
        float d0 = si - 64.0f + 16.0f * (float)seg;
        float2 a;
        a.x = __builtin_amdgcn_exp2f(negc2 * d0 * d0);
        a.y = __builtin_amdgcn_exp2f(negc2 * (2.0f * d0 + 1.0f));
        anc_sh[tid + NTHREADS * r] = a;
    }
    __syncthreads();

    // ---- Gamma0 column sums S_k into slab[1] (re-zeroed by iter t=0) ----
    {
        float tk[16];
        #pragma unroll
        for (int kk = 0; kk < 16; kk++) tk[kk] = topk_sh[seg * 16 + kk];
        float part[16];
        #pragma unroll
        for (int kk = 0; kk < 16; kk++) part[kk] = 0.0f;
        #pragma unroll 1
        for (int r = 0; r < ROWS_PT; r++) {
            float si = ss[team + NTEAMS * r];
            #pragma unroll
            for (int kk = 0; kk < 16; kk++) {
                float d = fabsf(tk[kk] - si);
                float e = __builtin_amdgcn_exp2f(d * lt);
                part[kk] += 1.0f / (1.0f + e) + 1e-20f;
            }
        }
        #pragma unroll
        for (int kk = 0; kk < 16; kk++)
            atomicAdd(&slab[1][h8 * KP1 + seg * 16 + kk], part[kk]);
    }
    __syncthreads();
    if (tid < KK) {
        float sum = 0.0f;
        #pragma unroll
        for (int g = 0; g < SLABR; g++) sum += slab[1][g * KP1 + tid];
        recS_sh[tid] = 1.0f / sum;
    }
    __syncthreads();

    // ---- Sinkhorn: 200 iterations ----
    for (int t = 0; t < MAX_ITER; t++) {
        float* sl  = &slab[t & 1][0];
        float* slz = &slab[(t + 1) & 1][0];

        float vloc[16], v64, cp[16], cp64;
        #pragma unroll
        for (int q = 0; q < 4; q++) {
            float4 vv = ((const float4*)(v_sh + seg * 16))[q];
            vloc[4 * q + 0] = vv.x; vloc[4 * q + 1] = vv.y;
            vloc[4 * q + 2] = vv.z; vloc[4 * q + 3] = vv.w;
        }
        v64 = v_sh[64];
        #pragma unroll
        for (int j = 0; j < 16; j++) cp[j] = 0.0f;
        cp64 = 0.0f;
        // zero next-iteration slab (readers done before this iter's entry)
        for (int q = tid; q < SLABR * KP1; q += NTHREADS) slz[q] = 0.0f;

        #pragma unroll 1
        for (int r = 0; r < ROWS_PT; r++) {
            float2 a = anc_sh[tid + NTHREADS * r];
            float g = a.x, tt = a.y;
            float G16[16];
            float p0 = 0.0f, p1 = 0.0f;
            #pragma unroll
            for (int jj = 0; jj < 16; jj += 2) {
                G16[jj] = g;     p0 = fmaf(g, vloc[jj],     p0); g *= tt; tt *= step;
                G16[jj + 1] = g; p1 = fmaf(g, vloc[jj + 1], p1); g *= tt; tt *= step;
            }
            float partial = p0 + p1;
            float gend = g;                      // g at j0+16; for seg==3 that's j=64
            if (seg == 3) partial = fmaf(gend, v64, partial);
            partial += __shfl_xor(partial, 1);
            partial += __shfl_xor(partial, 2);
            float u = inv_n / partial;           // IEEE div, matches ref
            #pragma unroll
            for (int jj = 0; jj < 16; jj++) cp[jj] = fmaf(G16[jj], u, cp[jj]);
            if (seg == 3) cp64 = fmaf(gend, u, cp64);
        }
        #pragma unroll
        for (int jj = 0; jj < 16; jj++)
            atomicAdd(&sl[h8 * KP1 + seg * 16 + jj], cp[jj]);
        if (seg == 3) atomicAdd(&sl[h8 * KP1 + 64], cp64);
        __syncthreads();
        if (tid < KP1) {
            float cs = 0.0f;
            #pragma unroll
            for (int g = 0; g < SLABR; g++) cs += sl[g * KP1 + tid];
            float nuj = (tid == KK) ? nu_last : inv_n;
            vprev_sh[tid] = v_sh[tid];           // keep v_{199} for final u
            v_sh[tid] = nuj / cs;
        }
        __syncthreads();
    }

    // ---- final pass A: u per row (vs v_prev) -> stash in srt (sort buf is dead) ----
    {
        float vp[16], vp64;
        #pragma unroll
        for (int j = 0; j < 16; j++) vp[j] = vprev_sh[seg * 16 + j];
        vp64 = vprev_sh[64];
        #pragma unroll 1
        for (int r = 0; r < ROWS_PT; r++) {
            float2 a = anc_sh[tid + NTHREADS * r];
            float g = a.x, tt = a.y;
            float p0 = 0.0f, p1 = 0.0f;
            #pragma unroll
            for (int jj = 0; jj < 16; jj += 2) {
                p0 = fmaf(g, vp[jj],     p0); g *= tt; tt *= step;
                p1 = fmaf(g, vp[jj + 1], p1); g *= tt; tt *= step;
            }
            float partial = p0 + p1;
            if (seg == 3) partial = fmaf(g, vp64, partial);
            partial += __shfl_xor(partial, 1);
            partial += __shfl_xor(partial, 2);
            if (seg == 0) srt[team + NTEAMS * r] = inv_n / partial;
        }
    }
    __syncthreads();

    // ---- final pass B: outputs + norm, exact exp per element (runs once) ----
    {
        float vloc[16], v64, tk[16], rs[16];
        #pragma unroll
        for (int j = 0; j < 16; j++) {
            vloc[j] = v_sh[seg * 16 + j];
            tk[j]   = topk_sh[seg * 16 + j];
            rs[j]   = recS_sh[seg * 16 + j];
        }
        v64 = v_sh[64];

        double npart = 0.0;
        #pragma unroll 1
        for (int r = 0; r < ROWS_PT; r++) {
            int row = team + NTEAMS * r;
            float si = ss[row];
            float u  = srt[row];
            float g0sum = 0.0f;
            float* orow = out + ((size_t)b * NN + row) * KK + seg * 16;
            #pragma unroll
            for (int q = 0; q < 4; q++) {
                float4 o;
                #define DO_K(kk_, fld) { const int kl = 4 * q + kk_;            \
                    const int k = seg * 16 + kl;                                \
                    float d_ = si - (float)(KK - k);                            \
                    float g_ = __builtin_amdgcn_exp2f(negc2 * d_ * d_);         \
                    float gm = (u * g_) * vloc[kl];                             \
                    float dd = fabsf(tk[kl] - si);                              \
                    float e  = __builtin_amdgcn_exp2f(dd * lt);                 \
                    float sg = 1.0f / (1.0f + e) + 1e-20f;                      \
                    float g0 = (sg * rs[kl]) * inv_n;                           \
                    g0sum += g0;                                                \
                    float df = gm - g0; npart += (double)df * (double)df;       \
                    o.fld = gm * 2048.0f; }
                DO_K(0, x) DO_K(1, y) DO_K(2, z) DO_K(3, w)
                #undef DO_K
                ((float4*)orow)[q] = o;
            }
            float gtot = g0sum;
            gtot += __shfl_xor(gtot, 1);
            gtot += __shfl_xor(gtot, 2);
            if (seg == 3) {
                float last = inv_n - gtot;
                last = fminf(fmaxf(last, 1e-20f), 1.0f);   // clip(.,1e-20,1-1e-20)
                float g64 = __builtin_amdgcn_exp2f(negc2 * si * si);
                float gm64 = (u * g64) * v64;
                float df = gm64 - last;
                npart += (double)df * (double)df;
            }
        }

        __syncthreads();
        red_sh[tid] = npart;
        __syncthreads();
        for (int s2 = NTHREADS / 2; s2 > 0; s2 >>= 1) {
            if (tid < s2) red_sh[tid] += red_sh[tid + s2];
            __syncthreads();
        }
        if (tid == 0) atomicAdd(norm_acc, red_sh[0]);
    }
}

// ---- kernel 3: finalize norm ----
__global__ void finalize_kernel(const double* __restrict__ norm_acc, float* __restrict__ out) {
    if (threadIdx.x == 0 && blockIdx.x == 0)
        out[(size_t)BS * NN * KK] = (float)sqrt(*norm_acc);
}

extern "C" void kernel_launch(void* const* d_in, const int* in_sizes, int n_in,
                              void* d_out, int out_size, void* d_ws, size_t ws_size,
                              hipStream_t stream) {
    const float* scores = (const float*)d_in[0];
    const float* W = (const float*)d_in[1];
    float* out = (float*)d_out;

    // ws layout: [0..3] max_enc(0), [4..7] inf_count(0),
    //            [8..15] norm_acc double(0), [16..19] min_enc(0xFFFFFFFF)
    unsigned* maxenc = (unsigned*)d_ws;
    unsigned* infc   = maxenc + 1;
    double*  nacc    = (double*)((char*)d_ws + 8);
    unsigned* minenc = (unsigned*)((char*)d_ws + 16);

    hipMemsetAsync(d_ws, 0, 16, stream);
    hipMemsetAsync((char*)d_ws + 16, 0xFF, 4, stream);

    hipLaunchKernelGGL(minmax_kernel, dim3(256), dim3(256), 0, stream,
                       scores, maxenc, minenc, infc);
    hipLaunchKernelGGL(sink_main, dim3(BS), dim3(NTHREADS), 0, stream,
                       scores, W, out, maxenc, minenc, infc, nacc);
    hipLaunchKernelGGL(finalize_kernel, dim3(1), dim3(64), 0, stream, nacc, out);
}

// Round 5
// 3284.509 us; speedup vs baseline: 3.5387x; 1.0466x over previous
//
#include <hip/hip_runtime.h>
#include <math.h>

#define BS 256
#define NN 2048
#define KK 64
#define KP1 65
#define NTHREADS 512
#define NTEAMS 128           // NTHREADS/4 teams; 4 lanes per team
#define ROWS_PT 16           // NN / NTEAMS rows per team
#define MAX_ITER 200
#define SLABR 8              // LDS reduction slab rows

// ---- monotone float<->uint encoding for atomic min/max ----
__device__ __forceinline__ unsigned enc_f32(float f) {
    unsigned b = __float_as_uint(f);
    return b ^ (unsigned)(((int)b >> 31) | (int)0x80000000);
}
__device__ __forceinline__ float dec_f32(unsigned e) {
    unsigned b = (e & 0x80000000u) ? (e & 0x7FFFFFFFu) : ~e;
    return __uint_as_float(b);
}

// ---- kernel 1: global min/max of scores (ignoring -inf for min), count -inf ----
__global__ void minmax_kernel(const float* __restrict__ s,
                              unsigned* __restrict__ maxenc,
                              unsigned* __restrict__ minenc,
                              unsigned* __restrict__ infc) {
    int tid = blockIdx.x * blockDim.x + threadIdx.x;
    int stride = gridDim.x * blockDim.x;
    float mx = -INFINITY, mn = INFINITY;
    unsigned cnt = 0;
    for (int i = tid; i < BS * NN; i += stride) {
        float v = s[i];
        if (isinf(v) && v < 0.0f) cnt++;
        else { mx = fmaxf(mx, v); mn = fminf(mn, v); }
    }
    for (int off = 32; off > 0; off >>= 1) {
        mx = fmaxf(mx, __shfl_down(mx, off));
        mn = fminf(mn, __shfl_down(mn, off));
        cnt += __shfl_down(cnt, off);
    }
    __shared__ float smx[8], smn[8];
    __shared__ unsigned scnt[8];
    int wid = threadIdx.x >> 6, lane = threadIdx.x & 63;
    if (lane == 0) { smx[wid] = mx; smn[wid] = mn; scnt[wid] = cnt; }
    __syncthreads();
    if (threadIdx.x == 0) {
        int nw = blockDim.x >> 6;
        for (int w = 1; w < nw; w++) { mx = fmaxf(mx, smx[w]); mn = fminf(mn, smn[w]); cnt += scnt[w]; }
        atomicMax(maxenc, enc_f32(mx));
        atomicMin(minenc, enc_f32(mn));
        if (cnt) atomicAdd(infc, cnt);
    }
}

// ---- kernel 2: per-batch sort + tau + Gamma0 + 200-iter Sinkhorn + outputs ----
// Team layout: 4 lanes per row-team; lane seg owns columns [seg*16, seg*16+16)
// (seg==3 also owns j=64 = endpoint of its recurrence).
// Anchors: g per (row,seg) in LDS (32 KB) + t0 per row (8 KB); segment ratio
// reconstructed as tt = t0 * Ds with lane-constant Ds = step^(16*seg).
// LDS ~65 KB -> 2 blocks/CU; inner loop interleaves 2 rows for ILP.
__global__ void __launch_bounds__(NTHREADS)
sink_main(const float* __restrict__ scores, const float* __restrict__ W,
          float* __restrict__ out,
          const unsigned* __restrict__ maxenc, const unsigned* __restrict__ minenc,
          const unsigned* __restrict__ infc, double* __restrict__ norm_acc)
{
    const int tid  = threadIdx.x;
    const int b    = blockIdx.x;
    const int team = tid >> 2;     // 0..127
    const int seg  = tid & 3;      // 0..3
    const int h8   = team & 7;     // slab row

    __shared__ float ss[NN];                                     // filled scores
    __shared__ float srt[NN];                                    // sort buf; later u per row
    __shared__ float ganc_sh[NN * 4] __attribute__((aligned(16))); // g anchor per (row,seg)
    __shared__ float tanc_sh[NN] __attribute__((aligned(16)));     // t0 per row
    __shared__ float v_sh[68] __attribute__((aligned(16)));      // v (65 used)
    __shared__ float vprev_sh[68];                               // v_{t-1}
    __shared__ float slab[2][SLABR * KP1] __attribute__((aligned(16)));
    __shared__ double red_sh[NTHREADS];
    __shared__ float recS_sh[KK];
    __shared__ float topk_sh[KK];

    const float LOG2E   = 1.4426950408889634f;
    const float inv_n   = 1.0f / 2048.0f;        // exact
    const float nu_last = 1984.0f / 2048.0f;     // exact

    // global scalars
    float smax = dec_f32(*maxenc);
    float smin = dec_f32(*minenc);
    unsigned icnt = *infc;
    float filled = smin - (smax - smin);
    float slo = (icnt > 0) ? filled : smin;
    // C.max() attained at an extreme s with anchor 0 or 64 (convexity)
    float cA = slo * slo, cB = (slo - 64.0f) * (slo - 64.0f);
    float cC = smax * smax, cD = (smax - 64.0f) * (smax - 64.0f);
    float Cmax = fmaxf(fmaxf(cA, cB), fmaxf(cC, cD));
    float negc2 = -(10.0f * LOG2E) / Cmax;       // exp(-C/Cmax/0.1) == exp2(d*d*negc2)
    float step = __builtin_amdgcn_exp2f(2.0f * negc2);          // t_{j+1}/t_j
    float Ds   = __builtin_amdgcn_exp2f(32.0f * negc2 * (float)seg); // t_seg/t_0

    // load + -inf fill
    for (int i = tid; i < NN; i += NTHREADS) {
        float v = scores[(size_t)b * NN + i];
        if (isinf(v) && v < 0.0f) v = filled;
        ss[i] = v; srt[i] = v;
    }
    __syncthreads();

    // bitonic sort (ascending)
    for (int size = 2; size <= NN; size <<= 1) {
        for (int stride = size >> 1; stride > 0; stride >>= 1) {
            #pragma unroll
            for (int pp = 0; pp < (NN / 2) / NTHREADS; pp++) {
                int p = tid + pp * NTHREADS;
                int lo = ((p & ~(stride - 1)) << 1) | (p & (stride - 1));
                int hi = lo + stride;
                bool up = ((lo & size) == 0);
                float x = srt[lo], y = srt[hi];
                if ((x > y) == up) { srt[lo] = y; srt[hi] = x; }
            }
            __syncthreads();
        }
    }

    // topk (descending) from sorted
    for (int k = tid; k < KK; k += NTHREADS) topk_sh[k] = srt[NN - 1 - k];

    // tau = sum(sorted * W), fp64 accumulate
    double tp = 0.0;
    for (int i = tid; i < NN; i += NTHREADS) tp += (double)srt[i] * (double)W[i];
    red_sh[tid] = tp;
    __syncthreads();
    for (int s2 = NTHREADS / 2; s2 > 0; s2 >>= 1) {
        if (tid < s2) red_sh[tid] += red_sh[tid + s2];
        __syncthreads();
    }
    float tau = (float)red_sh[0];
    float lt = LOG2E / tau;                      // sigma = 1/(1+exp2(|d|*lt))

    // init v, zero both slabs
    for (int j = tid; j < KP1; j += NTHREADS) v_sh[j] = 1.0f / 65.0f;
    for (int q = tid; q < 2 * SLABR * KP1; q += NTHREADS) ((float*)slab)[q] = 0.0f;

    // ---- anchors: g at j0 = seg*16 per (row,seg); t0 per row ----
    // d_j = si - (64-j); g_j = exp2(negc2*d_j^2); t_j = exp2(negc2*(2*d_j+1))
    #pragma unroll 1
    for (int r = 0; r < ROWS_PT; r++) {
        int row = team + NTEAMS * r;
        float si = ss[row];
        float d0 = si - 64.0f + 16.0f * (float)seg;
        ganc_sh[row * 4 + seg] = __builtin_amdgcn_exp2f(negc2 * d0 * d0);
        if (seg == 0)
            tanc_sh[row] = __builtin_amdgcn_exp2f(negc2 * (2.0f * d0 + 1.0f));
    }
    __syncthreads();

    // ---- Gamma0 column sums S_k into slab[1] (re-zeroed by iter t=0) ----
    {
        float tk[16];
        #pragma unroll
        for (int kk = 0; kk < 16; kk++) tk[kk] = topk_sh[seg * 16 + kk];
        float part[16];
        #pragma unroll
        for (int kk = 0; kk < 16; kk++) part[kk] = 0.0f;
        #pragma unroll 1
        for (int r = 0; r < ROWS_PT; r++) {
            float si = ss[team + NTEAMS * r];
            #pragma unroll
            for (int kk = 0; kk < 16; kk++) {
                float d = fabsf(tk[kk] - si);
                float e = __builtin_amdgcn_exp2f(d * lt);
                part[kk] += 1.0f / (1.0f + e) + 1e-20f;
            }
        }
        #pragma unroll
        for (int kk = 0; kk < 16; kk++)
            atomicAdd(&slab[1][h8 * KP1 + seg * 16 + kk], part[kk]);
    }
    __syncthreads();
    if (tid < KK) {
        float sum = 0.0f;
        #pragma unroll
        for (int g = 0; g < SLABR; g++) sum += slab[1][g * KP1 + tid];
        recS_sh[tid] = 1.0f / sum;
    }
    __syncthreads();

    // ---- Sinkhorn: 200 iterations, 2 rows in flight for ILP ----
    for (int t = 0; t < MAX_ITER; t++) {
        float* sl  = &slab[t & 1][0];
        float* slz = &slab[(t + 1) & 1][0];

        float vloc[16], v64, cp[16], cp64;
        #pragma unroll
        for (int q = 0; q < 4; q++) {
            float4 vv = ((const float4*)(v_sh + seg * 16))[q];
            vloc[4 * q + 0] = vv.x; vloc[4 * q + 1] = vv.y;
            vloc[4 * q + 2] = vv.z; vloc[4 * q + 3] = vv.w;
        }
        v64 = v_sh[64];
        #pragma unroll
        for (int j = 0; j < 16; j++) cp[j] = 0.0f;
        cp64 = 0.0f;
        // zero next-iteration slab (readers done before this iter's entry)
        for (int q = tid; q < SLABR * KP1; q += NTHREADS) slz[q] = 0.0f;

        #pragma unroll 1
        for (int pr = 0; pr < ROWS_PT / 2; pr++) {
            const int rowA = team + NTEAMS * (2 * pr);
            const int rowB = team + NTEAMS * (2 * pr + 1);
            float gA = ganc_sh[rowA * 4 + seg];
            float gB = ganc_sh[rowB * 4 + seg];
            float tA = tanc_sh[rowA] * Ds;
            float tB = tanc_sh[rowB] * Ds;
            float GA[16], GB[16];
            float pA0 = 0.f, pA1 = 0.f, pB0 = 0.f, pB1 = 0.f;
            #pragma unroll
            for (int jj = 0; jj < 16; jj += 2) {
                GA[jj]   = gA; pA0 = fmaf(gA, vloc[jj],   pA0); gA *= tA; tA *= step;
                GB[jj]   = gB; pB0 = fmaf(gB, vloc[jj],   pB0); gB *= tB; tB *= step;
                GA[jj+1] = gA; pA1 = fmaf(gA, vloc[jj+1], pA1); gA *= tA; tA *= step;
                GB[jj+1] = gB; pB1 = fmaf(gB, vloc[jj+1], pB1); gB *= tB; tB *= step;
            }
            float partA = pA0 + pA1;
            float partB = pB0 + pB1;
            float gAe = gA, gBe = gB;            // g at j0+16; for seg==3 that's j=64
            if (seg == 3) {
                partA = fmaf(gAe, v64, partA);
                partB = fmaf(gBe, v64, partB);
            }
            partA += __shfl_xor(partA, 1);
            partB += __shfl_xor(partB, 1);
            partA += __shfl_xor(partA, 2);
            partB += __shfl_xor(partB, 2);
            float uA = inv_n / partA;            // IEEE div, matches ref
            float uB = inv_n / partB;
            #pragma unroll
            for (int jj = 0; jj < 16; jj++)
                cp[jj] = fmaf(GA[jj], uA, fmaf(GB[jj], uB, cp[jj]));
            if (seg == 3) cp64 = fmaf(gAe, uA, fmaf(gBe, uB, cp64));
        }
        #pragma unroll
        for (int jj = 0; jj < 16; jj++)
            atomicAdd(&sl[h8 * KP1 + seg * 16 + jj], cp[jj]);
        if (seg == 3) atomicAdd(&sl[h8 * KP1 + 64], cp64);
        __syncthreads();
        if (tid < KP1) {
            float cs = 0.0f;
            #pragma unroll
            for (int g = 0; g < SLABR; g++) cs += sl[g * KP1 + tid];
            float nuj = (tid == KK) ? nu_last : inv_n;
            vprev_sh[tid] = v_sh[tid];           // keep v_{199} for final u
            v_sh[tid] = nuj / cs;
        }
        __syncthreads();
    }

    // ---- final pass A: u per row (vs v_prev) -> stash in srt (sort buf dead) ----
    {
        float vp[16], vp64;
        #pragma unroll
        for (int j = 0; j < 16; j++) vp[j] = vprev_sh[seg * 16 + j];
        vp64 = vprev_sh[64];
        #pragma unroll 1
        for (int r = 0; r < ROWS_PT; r++) {
            int row = team + NTEAMS * r;
            float g = ganc_sh[row * 4 + seg];
            float tt = tanc_sh[row] * Ds;
            float p0 = 0.0f, p1 = 0.0f;
            #pragma unroll
            for (int jj = 0; jj < 16; jj += 2) {
                p0 = fmaf(g, vp[jj],     p0); g *= tt; tt *= step;
                p1 = fmaf(g, vp[jj + 1], p1); g *= tt; tt *= step;
            }
            float partial = p0 + p1;
            if (seg == 3) partial = fmaf(g, vp64, partial);
            partial += __shfl_xor(partial, 1);
            partial += __shfl_xor(partial, 2);
            if (seg == 0) srt[row] = inv_n / partial;
        }
    }
    __syncthreads();

    // ---- final pass B: outputs + norm, exact exp per element (runs once) ----
    {
        float vloc[16], v64, tk[16], rs[16];
        #pragma unroll
        for (int j = 0; j < 16; j++) {
            vloc[j] = v_sh[seg * 16 + j];
            tk[j]   = topk_sh[seg * 16 + j];
            rs[j]   = recS_sh[seg * 16 + j];
        }
        v64 = v_sh[64];

        double npart = 0.0;
        #pragma unroll 1
        for (int r = 0; r < ROWS_PT; r++) {
            int row = team + NTEAMS * r;
            float si = ss[row];
            float u  = srt[row];
            float g0sum = 0.0f;
            float* orow = out + ((size_t)b * NN + row) * KK + seg * 16;
            #pragma unroll
            for (int q = 0; q < 4; q++) {
                float4 o;
                #define DO_K(kk_, fld) { const int kl = 4 * q + kk_;            \
                    const int k = seg * 16 + kl;                                \
                    float d_ = si - (float)(KK - k);                            \
                    float g_ = __builtin_amdgcn_exp2f(negc2 * d_ * d_);         \
                    float gm = (u * g_) * vloc[kl];                             \
                    float dd = fabsf(tk[kl] - si);                              \
                    float e  = __builtin_amdgcn_exp2f(dd * lt);                 \
                    float sg = 1.0f / (1.0f + e) + 1e-20f;                      \
                    float g0 = (sg * rs[kl]) * inv_n;                           \
                    g0sum += g0;                                                \
                    float df = gm - g0; npart += (double)df * (double)df;       \
                    o.fld = gm * 2048.0f; }
                DO_K(0, x) DO_K(1, y) DO_K(2, z) DO_K(3, w)
                #undef DO_K
                ((float4*)orow)[q] = o;
            }
            float gtot = g0sum;
            gtot += __shfl_xor(gtot, 1);
            gtot += __shfl_xor(gtot, 2);
            if (seg == 3) {
                float last = inv_n - gtot;
                last = fminf(fmaxf(last, 1e-20f), 1.0f);   // clip(.,1e-20,1-1e-20)
                float g64 = __builtin_amdgcn_exp2f(negc2 * si * si);
                float gm64 = (u * g64) * v64;
                float df = gm64 - last;
                npart += (double)df * (double)df;
            }
        }

        __syncthreads();
        red_sh[tid] = npart;
        __syncthreads();
        for (int s2 = NTHREADS / 2; s2 > 0; s2 >>= 1) {
            if (tid < s2) red_sh[tid] += red_sh[tid + s2];
            __syncthreads();
        }
        if (tid == 0) atomicAdd(norm_acc, red_sh[0]);
    }
}

// ---- kernel 3: finalize norm ----
__global__ void finalize_kernel(const double* __restrict__ norm_acc, float* __restrict__ out) {
    if (threadIdx.x == 0 && blockIdx.x == 0)
        out[(size_t)BS * NN * KK] = (float)sqrt(*norm_acc);
}

extern "C" void kernel_launch(void* const* d_in, const int* in_sizes, int n_in,
                              void* d_out, int out_size, void* d_ws, size_t ws_size,
                              hipStream_t stream) {
    const float* scores = (const float*)d_in[0];
    const float* W = (const float*)d_in[1];
    float* out = (float*)d_out;

    // ws layout: [0..3] max_enc(0), [4..7] inf_count(0),
    //            [8..15] norm_acc double(0), [16..19] min_enc(0xFFFFFFFF)
    unsigned* maxenc = (unsigned*)d_ws;
    unsigned* infc   = maxenc + 1;
    double*  nacc    = (double*)((char*)d_ws + 8);
    unsigned* minenc = (unsigned*)((char*)d_ws + 16);

    hipMemsetAsync(d_ws, 0, 16, stream);
    hipMemsetAsync((char*)d_ws + 16, 0xFF, 4, stream);

    hipLaunchKernelGGL(minmax_kernel, dim3(256), dim3(256), 0, stream,
                       scores, maxenc, minenc, infc);
    hipLaunchKernelGGL(sink_main, dim3(BS), dim3(NTHREADS), 0, stream,
                       scores, W, out, maxenc, minenc, infc, nacc);
    hipLaunchKernelGGL(finalize_kernel, dim3(1), dim3(64), 0, stream, nacc, out);
}